// Round 8
// baseline (314.178 us; speedup 1.0000x reference)
//
#include <hip/hip_runtime.h>
#include <math.h>

namespace {

constexpr float kInv512 = 1.0f / 512.0f;

struct cpx { float x, y; };
__device__ __forceinline__ cpx cadd(cpx a, cpx b){ return {a.x+b.x, a.y+b.y}; }
__device__ __forceinline__ cpx csub(cpx a, cpx b){ return {a.x-b.x, a.y-b.y}; }
__device__ __forceinline__ cpx cmul(cpx a, cpx b){ return {a.x*b.x - a.y*b.y, a.x*b.y + a.y*b.x}; }

// multiply by (S<0 ? -i : +i)
template<int S>
__device__ __forceinline__ cpx Jrot(cpx z){
  return (S < 0) ? cpx{ z.y, -z.x } : cpx{ -z.y, z.x };
}

// natural-order 8-point DFT, A[k] = sum_n A[n] * exp(S*2*pi*i*n*k/8)
template<int S>
__device__ __forceinline__ void dft8(cpx* A){
  const float s2 = 0.70710678118654752440f;
  cpx t0=A[0], t1=A[4], t2=A[2], t3=A[6], t4=A[1], t5=A[5], t6=A[3], t7=A[7];
  cpx b0=cadd(t0,t1), b1=csub(t0,t1), b2=cadd(t2,t3), b3=csub(t2,t3);
  cpx b4=cadd(t4,t5), b5=csub(t4,t5), b6=cadd(t6,t7), b7=csub(t6,t7);
  cpx jb3=Jrot<S>(b3), jb7=Jrot<S>(b7);
  cpx c0=cadd(b0,b2), c2=csub(b0,b2), c1=cadd(b1,jb3), c3=csub(b1,jb3);
  cpx c4=cadd(b4,b6), c6=csub(b4,b6), c5=cadd(b5,jb7), c7=csub(b5,jb7);
  cpx jc6=Jrot<S>(c6);
  cpx w5, w7;
  if (S < 0) {
    w5 = cpx{ s2*(c5.x + c5.y), s2*(c5.y - c5.x) };   // w8^1 * c5
    w7 = cpx{ s2*(c7.y - c7.x), -s2*(c7.x + c7.y) };  // w8^3 * c7
  } else {
    w5 = cpx{ s2*(c5.x - c5.y), s2*(c5.x + c5.y) };
    w7 = cpx{ -s2*(c7.x + c7.y), s2*(c7.x - c7.y) };
  }
  A[0]=cadd(c0,c4); A[4]=csub(c0,c4);
  A[2]=cadd(c2,jc6); A[6]=csub(c2,jc6);
  A[1]=cadd(c1,w5);  A[5]=csub(c1,w5);
  A[3]=cadd(c3,w7);  A[7]=csub(c3,w7);
}

__device__ __forceinline__ int slotN(int n){
  return 73*(n >> 6) + (n & 63);
}

__device__ __forceinline__ float bperm(int addr, float v){
  return __int_as_float(__builtin_amdgcn_ds_bpermute(addr, __float_as_int(v)));
}

// ---------------- kernel 0: transpose cw [E][F][H][2] -> cwT [E][pair][F][4] ----------------
// One float4 per (f, channel-pair). Reads 2KB-contiguous per instr; each thread
// writes sequential 16B chunks (merge in L2; table stays L3-resident).
__global__ __launch_bounds__(128) void cwt_kernel(
    const float* __restrict__ cw, float* __restrict__ cwT)
{
  int e = blockIdx.x, fg = blockIdx.y, pr = threadIdx.x;
  const float4* src = (const float4*)cw;
  float4* dst = (float4*)cwT;
  int nf = (fg == 15) ? 17 : 16;
  int f0 = fg * 16;
  for (int i = 0; i < nf; ++i){
    int f = f0 + i;
    dst[(e*128 + pr)*257 + f] = src[(e*257 + f)*128 + pr];
  }
}

// ------------- kernel 1: gate = softmax(mean-pool MLP) / 512, single HBM pass -------------
__global__ __launch_bounds__(256) void gate_kernel(
    const float* __restrict__ x, const float* __restrict__ mlp_w,
    const float* __restrict__ mlp_b, float* __restrict__ gate)
{
  __shared__ float tile[32][257];
  __shared__ float red[32];
  __shared__ int icnt[4];
  int b = blockIdx.x, t = threadIdx.x;
  const float* xb = x + (size_t)b * 131072;

  float colsum = 0.f;
  int cnt = 0;
  for (int ch = 0; ch < 16; ++ch){
    #pragma unroll
    for (int sr = 0; sr < 32; ++sr){
      float v = xb[(ch*32 + sr)*256 + t];
      colsum += v;
      tile[sr][t] = v;
    }
    __syncthreads();
    {
      int row = t >> 3, base = (t & 7) * 32;
      float rs = 0.f;
      #pragma unroll
      for (int j = 0; j < 32; ++j) rs += tile[row][base + j];
      rs += __shfl_xor(rs, 1);
      rs += __shfl_xor(rs, 2);
      rs += __shfl_xor(rs, 4);
      if ((t & 7) == 0) cnt += (rs != 0.f) ? 1 : 0;
    }
    __syncthreads();
  }

  for (int m=1;m<64;m<<=1) cnt += __shfl_xor(cnt, m);
  int wv = t >> 6, ln = t & 63;
  if (ln == 0) icnt[wv] = cnt;
  __syncthreads();
  float valid = (float)(icnt[0]+icnt[1]+icnt[2]+icnt[3]);
  float gi = colsum * (50.0f / ((valid + 1e-4f) * 512.0f));

  float pl[8];
  const float4* w4 = (const float4*)(mlp_w + (size_t)t*8);
  float4 wa = w4[0], wb = w4[1];
  pl[0]=gi*wa.x; pl[1]=gi*wa.y; pl[2]=gi*wa.z; pl[3]=gi*wa.w;
  pl[4]=gi*wb.x; pl[5]=gi*wb.y; pl[6]=gi*wb.z; pl[7]=gi*wb.w;
  #pragma unroll
  for (int e=0;e<8;++e){
    float v = pl[e];
    for (int m=1;m<64;m<<=1) v += __shfl_xor(v, m);
    pl[e] = v;
  }
  if (ln == 0){
    #pragma unroll
    for (int e=0;e<8;++e) red[wv*8+e] = pl[e];
  }
  __syncthreads();
  if (t < 8){
    float lg = red[0*8+t]+red[1*8+t]+red[2*8+t]+red[3*8+t] + mlp_b[t];
    float mx = lg;
    for (int m=1;m<8;m<<=1) mx = fmaxf(mx, __shfl_xor(mx, m, 8));
    float ex = expf(lg - mx);
    float sm = ex;
    for (int m=1;m<8;m<<=1) sm += __shfl_xor(sm, m, 8);
    gate[b*8 + t] = ex / sm * kInv512;
  }
}

// ------- kernel 2 (primary): FFT with in-register Hermitian filter -------
// Lane map: after fwd stage 3, lane l holds Z[klow+64d], klow = bitswap(l).
// Mirror set lives in lane sig(64-klow) -> 16 bpermutes replace the LDS
// phase-C round-trip; inverse stage 1 consumes filter output in registers
// (lane acts as virtual lane v=klow). 2 barriers total, 96 LDS b64/thread.
// Plain __launch_bounds__(512): forcing min-waves spilled in r3/r4
// (canary: WRITE_SIZE must stay exactly 131072 KB).
__global__ __launch_bounds__(512) void fft_kernel2(
    const float* __restrict__ x, const float* __restrict__ cwT,
    const float* __restrict__ gate, float* __restrict__ out)
{
  __shared__ float2 zz[8][584];   // 37.4 KB
  int t = threadIdx.x;
  int hg = blockIdx.x, b = blockIdx.y;
  int h_base = hg * 16;
  const float* xb = x + (size_t)b * 131072;
  float* ob = out + (size_t)b * 131072;

  int p = t >> 6, l = t & 63;
  float2* zp = zz[p];
  int k1r = l >> 3, d3 = l & 7;
  int klow = k1r + 8*d3;                    // bitswap(l)
  int mk = (64 - klow) & 63;
  int lmir = (mk >> 3) + 8*(mk & 7);        // bitswap(mk)
  int ad = lmir << 2;

  // gate (uniform per block)
  float g[8];
  #pragma unroll
  for (int e=0;e<8;++e) g[e] = gate[b*8 + e];

  // phase A: float2 coalesced load into LDS (all 8 pairs cooperatively)
  #pragma unroll
  for (int it=0; it<8; ++it){
    float2 v = *(const float2*)(xb + (it*64 + (t>>3))*256 + h_base + 2*(t & 7));
    zz[t & 7][73*it + (t >> 3)] = v;
  }

  // wmix family-1: w((klow + 64j)) for this wave's pair, mixed over experts.
  // cwT loads: fixed (e,j) -> 64 lanes read 64 consecutive float4 = 1KB.
  int pg = hg*8 + p;
  const float4* cT = (const float4*)cwT;
  float4 acc1[4];
  #pragma unroll
  for (int j=0;j<4;++j) acc1[j] = make_float4(kInv512, 0.f, kInv512, 0.f);
  #pragma unroll
  for (int e=0;e<8;++e){
    int base = (e*128 + pg)*257 + klow;
    float ge = g[e];
    #pragma unroll
    for (int j=0;j<4;++j){
      float4 c = cT[base + 64*j];
      acc1[j].x += ge*c.x; acc1[j].y += ge*c.y;
      acc1[j].z += ge*c.z; acc1[j].w += ge*c.w;
    }
  }
  // family-2 = mirror lane's family-1 (w((64-klow) + 64j))
  float4 acc2[4];
  #pragma unroll
  for (int j=0;j<4;++j){
    acc2[j].x = bperm(ad, acc1[j].x);
    acc2[j].y = bperm(ad, acc1[j].y);
    acc2[j].z = bperm(ad, acc1[j].z);
    acc2[j].w = bperm(ad, acc1[j].w);
  }
  if (l == 0){
    // lane 0 needs fam2 = w at {64,128,192,256}
    acc2[0] = acc1[1]; acc2[1] = acc1[2]; acc2[2] = acc1[3];
    float4 a256 = make_float4(kInv512, 0.f, kInv512, 0.f);
    #pragma unroll
    for (int e=0;e<8;++e){
      float4 c = cT[(e*128 + pg)*257 + 256];
      a256.x += g[e]*c.x; a256.y += g[e]*c.y;
      a256.z += g[e]*c.z; a256.w += g[e]*c.w;
    }
    acc2[3] = a256;
  }
  __syncthreads();

  // ---- forward FFT: stages 1-2 via LDS, stage 3 ends in registers ----
  cpx a[8];
  {
    cpx tw1[7], tw2[7];
    float th1 = -6.28318530717958647692f * (1.0f/512.0f) * (float)l;
    cpx w1; __sincosf(th1, &w1.y, &w1.x);
    tw1[0] = w1;
    #pragma unroll
    for (int k=1;k<7;++k) tw1[k] = cmul(tw1[k-1], w1);
    float th2 = -6.28318530717958647692f * (1.0f/64.0f) * (float)d3;
    cpx w2; __sincosf(th2, &w2.y, &w2.x);
    tw2[0] = w2;
    #pragma unroll
    for (int k=1;k<7;++k) tw2[k] = cmul(tw2[k-1], w2);

    #pragma unroll
    for (int j=0;j<8;++j){ float2 v = zp[73*j + l]; a[j] = {v.x, v.y}; }
    dft8<-1>(a);
    #pragma unroll
    for (int k=1;k<8;++k) a[k] = cmul(a[k], tw1[k-1]);
    #pragma unroll
    for (int k1=0;k1<8;++k1) zp[73*k1 + l] = make_float2(a[k1].x, a[k1].y);

    #pragma unroll
    for (int aa=0;aa<8;++aa){ float2 v = zp[73*k1r + 8*aa + d3]; a[aa] = {v.x, v.y}; }
    dft8<-1>(a);
    #pragma unroll
    for (int c=1;c<8;++c) a[c] = cmul(a[c], tw2[c-1]);
    #pragma unroll
    for (int c=0;c<8;++c) zp[73*k1r + 8*c + d3] = make_float2(a[c].x, a[c].y);

    #pragma unroll
    for (int b8=0;b8<8;++b8){ float2 v = zp[73*k1r + 8*d3 + b8]; a[b8] = {v.x, v.y}; }
    dft8<-1>(a);
    // a[d] = Z[klow + 64d]
  }

  // ---- Hermitian exchange + filter, all in registers ----
  cpx Zm[8];
  #pragma unroll
  for (int d=0;d<8;++d){
    Zm[d].x = bperm(ad, a[7-d].x);
    Zm[d].y = bperm(ad, a[7-d].y);
  }
  if (l == 0){
    #pragma unroll
    for (int d=0;d<8;++d) Zm[d] = a[(8-d)&7];
  }
  cpx q[8];
  #pragma unroll
  for (int d=0;d<8;++d){
    float4 w = (d < 4) ? acc1[d] : acc2[7-d];
    float sg = (d < 4) ? 1.f : -1.f;        // conj(w) for f > 256
    float w0x = w.x, w0y = sg*w.y, w1x = w.z, w1y = sg*w.w;
    float X0x = 0.5f*(a[d].x + Zm[d].x), X0y = 0.5f*(a[d].y - Zm[d].y);
    float X1x = 0.5f*(a[d].y + Zm[d].y), X1y = 0.5f*(Zm[d].x - a[d].x);
    float Y0x = X0x*w0x - X0y*w0y, Y0y = X0x*w0y + X0y*w0x;
    float Y1x = X1x*w1x - X1y*w1y, Y1y = X1x*w1y + X1y*w1x;
    q[d] = { Y0x - Y1y, Y0y + Y1x };
  }
  if (l == 0){
    // f=0 (DC) and f=256 (Nyquist): imag of products discarded (numpy irfft)
    q[0] = { a[0].x*acc1[0].x, a[0].y*acc1[0].z };
    q[4] = { a[4].x*acc2[3].x, a[4].y*acc2[3].z };
  }

  // ---- inverse FFT: lane acts as virtual lane v = klow; stage 1 from regs ----
  {
    int v = klow, vk1r = d3, vd3 = k1r;     // bit-swapped roles
    cpx tw1[7], tw2[7];
    float th1 = 6.28318530717958647692f * (1.0f/512.0f) * (float)v;
    cpx w1; __sincosf(th1, &w1.y, &w1.x);
    tw1[0] = w1;
    #pragma unroll
    for (int k=1;k<7;++k) tw1[k] = cmul(tw1[k-1], w1);
    float th2 = 6.28318530717958647692f * (1.0f/64.0f) * (float)vd3;
    cpx w2; __sincosf(th2, &w2.y, &w2.x);
    tw2[0] = w2;
    #pragma unroll
    for (int k=1;k<7;++k) tw2[k] = cmul(tw2[k-1], w2);

    dft8<1>(q);
    #pragma unroll
    for (int k=1;k<8;++k) q[k] = cmul(q[k], tw1[k-1]);
    #pragma unroll
    for (int k1=0;k1<8;++k1) zp[73*k1 + v] = make_float2(q[k1].x, q[k1].y);

    #pragma unroll
    for (int aa=0;aa<8;++aa){ float2 vv = zp[73*vk1r + 8*aa + vd3]; q[aa] = {vv.x, vv.y}; }
    dft8<1>(q);
    #pragma unroll
    for (int c=1;c<8;++c) q[c] = cmul(q[c], tw2[c-1]);
    #pragma unroll
    for (int c=0;c<8;++c) zp[73*vk1r + 8*c + vd3] = make_float2(q[c].x, q[c].y);

    #pragma unroll
    for (int b8=0;b8<8;++b8){ float2 vv = zp[73*vk1r + 8*vd3 + b8]; q[b8] = {vv.x, vv.y}; }
    dft8<1>(q);
    // vklow = vk1r + 8*vd3 = l: natural-order output at zp[73*d + l]
    #pragma unroll
    for (int d=0;d<8;++d) zp[73*d + l] = make_float2(q[d].x, q[d].y);
  }
  __syncthreads();

  // phase E: float2 coalesced writeout
  #pragma unroll
  for (int it=0; it<8; ++it){
    float2 v = zz[t & 7][73*it + (t >> 3)];
    *(float2*)(ob + (it*64 + (t>>3))*256 + h_base + 2*(t & 7)) = v;
  }
}

// ------- kernel 2 (fallback, r6-proven): used when ws_size can't hold cwT -------
__global__ __launch_bounds__(512) void fft_kernel_fb(
    const float* __restrict__ x, const float* __restrict__ cw,
    const float* __restrict__ gate, float* __restrict__ out)
{
  __shared__ float2 zz[8][584];
  int t = threadIdx.x;
  int hg = blockIdx.x, b = blockIdx.y;
  int h_base = hg * 16;
  const float* xb = x + (size_t)b * 131072;
  float* ob = out + (size_t)b * 131072;

  int p = t >> 6, l = t & 63;
  float2* zp = zz[p];
  int k1r = l >> 3, d3 = l & 7;

  cpx tw1[7], tw2[7];
  {
    float th1 = -6.28318530717958647692f * (1.0f/512.0f) * (float)l;
    cpx w1; __sincosf(th1, &w1.y, &w1.x);
    tw1[0] = w1;
    #pragma unroll
    for (int k=1;k<7;++k) tw1[k] = cmul(tw1[k-1], w1);
    float th2 = -6.28318530717958647692f * (1.0f/64.0f) * (float)d3;
    cpx w2; __sincosf(th2, &w2.y, &w2.x);
    tw2[0] = w2;
    #pragma unroll
    for (int k=1;k<7;++k) tw2[k] = cmul(tw2[k-1], w2);
  }

  float g[8];
  #pragma unroll
  for (int e=0;e<8;++e) g[e] = gate[b*8 + e];

  #pragma unroll
  for (int it=0; it<8; ++it){
    int s = it*64 + (t >> 3);
    float2 v = *(const float2*)(xb + s*256 + h_base + 2*(t & 7));
    zz[t & 7][73*it + (t >> 3)] = v;
  }
  __syncthreads();

  {
    cpx a[8];
    #pragma unroll
    for (int j=0;j<8;++j){ float2 v = zp[73*j + l]; a[j] = {v.x, v.y}; }
    dft8<-1>(a);
    #pragma unroll
    for (int k=1;k<8;++k) a[k] = cmul(a[k], tw1[k-1]);
    #pragma unroll
    for (int k1=0;k1<8;++k1) zp[73*k1 + l] = make_float2(a[k1].x, a[k1].y);
    #pragma unroll
    for (int aa=0;aa<8;++aa){ float2 v = zp[73*k1r + 8*aa + d3]; a[aa] = {v.x, v.y}; }
    dft8<-1>(a);
    #pragma unroll
    for (int c=1;c<8;++c) a[c] = cmul(a[c], tw2[c-1]);
    #pragma unroll
    for (int c=0;c<8;++c) zp[73*k1r + 8*c + d3] = make_float2(a[c].x, a[c].y);
    #pragma unroll
    for (int b8=0;b8<8;++b8){ float2 v = zp[73*k1r + 8*d3 + b8]; a[b8] = {v.x, v.y}; }
    dft8<-1>(a);
    int klow = k1r + 8*d3;
    #pragma unroll
    for (int d=0;d<8;++d) zp[73*d + klow] = make_float2(a[d].x, a[d].y);
  }
  __syncthreads();

  {
    int pc = t & 7, fq = t >> 3;
    float2* zq = zz[pc];
    int hc = h_base + 2*pc;
    #pragma unroll
    for (int it=0; it<4; ++it){
      int f = it*64 + fq;
      float2 Zf = zq[73*it + fq];
      int m = (512 - f) & 511;
      float2 Zm = zq[slotN(m)];
      float X0x = 0.5f*(Zf.x + Zm.x), X0y = 0.5f*(Zf.y - Zm.y);
      float X1x = 0.5f*(Zf.y + Zm.y), X1y = 0.5f*(Zm.x - Zf.x);
      float w0x = kInv512, w0y = 0.f, w1x = kInv512, w1y = 0.f;
      const float* cwf = cw + ((size_t)f*256 + hc)*2;
      #pragma unroll
      for (int e=0;e<8;++e){
        float4 cv = *(const float4*)(cwf + (size_t)e*131584);
        w0x += g[e]*cv.x; w0y += g[e]*cv.y;
        w1x += g[e]*cv.z; w1y += g[e]*cv.w;
      }
      float Y0x = X0x*w0x - X0y*w0y, Y0y = X0x*w0y + X0y*w0x;
      float Y1x = X1x*w1x - X1y*w1y, Y1y = X1x*w1y + X1y*w1x;
      if (f == 0){ Y0y = 0.f; Y1y = 0.f; }
      zq[73*it + fq] = make_float2(Y0x - Y1y, Y0y + Y1x);
      zq[slotN(m)]   = make_float2(Y0x + Y1y, Y1x - Y0y);
    }
    if (t < 8){
      float2* zn = zz[t];
      int hn = h_base + 2*t;
      float2 Zf = zn[292];
      float w0x = kInv512, w1x = kInv512;
      const float* cwf = cw + ((size_t)256*256 + hn)*2;
      #pragma unroll
      for (int e=0;e<8;++e){
        float4 cv = *(const float4*)(cwf + (size_t)e*131584);
        w0x += g[e]*cv.x; w1x += g[e]*cv.z;
      }
      zn[292] = make_float2(Zf.x*w0x, Zf.y*w1x);
    }
  }
  __syncthreads();

  {
    cpx a[8];
    #pragma unroll
    for (int j=0;j<8;++j){ float2 v = zp[73*j + l]; a[j] = {v.x, v.y}; }
    dft8<1>(a);
    #pragma unroll
    for (int k=1;k<8;++k){ cpx w = tw1[k-1]; a[k] = cpx{ a[k].x*w.x + a[k].y*w.y, a[k].y*w.x - a[k].x*w.y }; }
    #pragma unroll
    for (int k1=0;k1<8;++k1) zp[73*k1 + l] = make_float2(a[k1].x, a[k1].y);
    #pragma unroll
    for (int aa=0;aa<8;++aa){ float2 v = zp[73*k1r + 8*aa + d3]; a[aa] = {v.x, v.y}; }
    dft8<1>(a);
    #pragma unroll
    for (int c=1;c<8;++c){ cpx w = tw2[c-1]; a[c] = cpx{ a[c].x*w.x + a[c].y*w.y, a[c].y*w.x - a[c].x*w.y }; }
    #pragma unroll
    for (int c=0;c<8;++c) zp[73*k1r + 8*c + d3] = make_float2(a[c].x, a[c].y);
    #pragma unroll
    for (int b8=0;b8<8;++b8){ float2 v = zp[73*k1r + 8*d3 + b8]; a[b8] = {v.x, v.y}; }
    dft8<1>(a);
    int klow = k1r + 8*d3;
    #pragma unroll
    for (int d=0;d<8;++d) zp[73*d + klow] = make_float2(a[d].x, a[d].y);
  }
  __syncthreads();

  #pragma unroll
  for (int it=0; it<8; ++it){
    int s = it*64 + (t >> 3);
    float2 v = zz[t & 7][73*it + (t >> 3)];
    *(float2*)(ob + s*256 + h_base + 2*(t & 7)) = v;
  }
}

// ---------------- kernel 3: in-place LayerNorm over H=256 ----------------
__global__ __launch_bounds__(256) void ln_kernel(
    float* __restrict__ io, const float* __restrict__ gamma,
    const float* __restrict__ beta)
{
  int t = threadIdx.x;
  int row = blockIdx.x*4 + (t >> 6);
  int ln = t & 63;
  float4* pr = (float4*)(io + (size_t)row * 256);
  float4 v = pr[ln];
  float s = (v.x+v.y)+(v.z+v.w);
  float q = (v.x*v.x + v.y*v.y) + (v.z*v.z + v.w*v.w);
  for (int m=1;m<64;m<<=1){ s += __shfl_xor(s, m); q += __shfl_xor(q, m); }
  float mean = s * (1.0f/256.0f);
  float var  = q * (1.0f/256.0f) - mean*mean;
  float rstd = rsqrtf(var + 1e-12f);
  const float4 gm = ((const float4*)gamma)[ln];
  const float4 bt = ((const float4*)beta)[ln];
  float4 o;
  o.x = (v.x - mean)*rstd*gm.x + bt.x;
  o.y = (v.y - mean)*rstd*gm.y + bt.y;
  o.z = (v.z - mean)*rstd*gm.z + bt.z;
  o.w = (v.w - mean)*rstd*gm.w + bt.w;
  pr[ln] = o;
}

} // anonymous namespace

extern "C" void kernel_launch(void* const* d_in, const int* in_sizes, int n_in,
                              void* d_out, int out_size, void* d_ws, size_t ws_size,
                              hipStream_t stream) {
  const float* x     = (const float*)d_in[0];
  const float* cw    = (const float*)d_in[1];
  const float* mlp_w = (const float*)d_in[2];
  const float* mlp_b = (const float*)d_in[3];
  const float* gamma = (const float*)d_in[4];
  const float* beta  = (const float*)d_in[5];
  float* out  = (float*)d_out;          // h-scratch, then LN'd in place
  float* gate = (float*)d_ws;           // 2048 floats (8 KB)

  hipLaunchKernelGGL(gate_kernel, dim3(256), dim3(256), 0, stream,
                     x, mlp_w, mlp_b, gate);

  const size_t cwT_bytes = (size_t)8*128*257*4*sizeof(float); // 4.21 MB
  if (ws_size >= 8192 + cwT_bytes){
    float* cwT = (float*)((char*)d_ws + 8192);
    hipLaunchKernelGGL(cwt_kernel, dim3(8,16), dim3(128), 0, stream, cw, cwT);
    hipLaunchKernelGGL(fft_kernel2, dim3(16, 256), dim3(512), 0, stream,
                       x, cwT, gate, out);
  } else {
    hipLaunchKernelGGL(fft_kernel_fb, dim3(16, 256), dim3(512), 0, stream,
                       x, cw, gate, out);
  }

  hipLaunchKernelGGL(ln_kernel, dim3(32768), dim3(256), 0, stream,
                     out, gamma, beta);
}

// Round 9
// 241.018 us; speedup vs baseline: 1.3035x; 1.3035x over previous
//
#include <hip/hip_runtime.h>
#include <math.h>

namespace {

constexpr float kInv512 = 1.0f / 512.0f;

struct cpx { float x, y; };
__device__ __forceinline__ cpx cadd(cpx a, cpx b){ return {a.x+b.x, a.y+b.y}; }
__device__ __forceinline__ cpx csub(cpx a, cpx b){ return {a.x-b.x, a.y-b.y}; }
__device__ __forceinline__ cpx cmul(cpx a, cpx b){ return {a.x*b.x - a.y*b.y, a.x*b.y + a.y*b.x}; }

// multiply by (S<0 ? -i : +i)
template<int S>
__device__ __forceinline__ cpx Jrot(cpx z){
  return (S < 0) ? cpx{ z.y, -z.x } : cpx{ -z.y, z.x };
}

// natural-order 8-point DFT, A[k] = sum_n A[n] * exp(S*2*pi*i*n*k/8)
template<int S>
__device__ __forceinline__ void dft8(cpx* A){
  const float s2 = 0.70710678118654752440f;
  cpx t0=A[0], t1=A[4], t2=A[2], t3=A[6], t4=A[1], t5=A[5], t6=A[3], t7=A[7];
  cpx b0=cadd(t0,t1), b1=csub(t0,t1), b2=cadd(t2,t3), b3=csub(t2,t3);
  cpx b4=cadd(t4,t5), b5=csub(t4,t5), b6=cadd(t6,t7), b7=csub(t6,t7);
  cpx jb3=Jrot<S>(b3), jb7=Jrot<S>(b7);
  cpx c0=cadd(b0,b2), c2=csub(b0,b2), c1=cadd(b1,jb3), c3=csub(b1,jb3);
  cpx c4=cadd(b4,b6), c6=csub(b4,b6), c5=cadd(b5,jb7), c7=csub(b5,jb7);
  cpx jc6=Jrot<S>(c6);
  cpx w5, w7;
  if (S < 0) {
    w5 = cpx{ s2*(c5.x + c5.y), s2*(c5.y - c5.x) };   // w8^1 * c5
    w7 = cpx{ s2*(c7.y - c7.x), -s2*(c7.x + c7.y) };  // w8^3 * c7
  } else {
    w5 = cpx{ s2*(c5.x - c5.y), s2*(c5.x + c5.y) };
    w7 = cpx{ -s2*(c7.x + c7.y), s2*(c7.x - c7.y) };
  }
  A[0]=cadd(c0,c4); A[4]=csub(c0,c4);
  A[2]=cadd(c2,jc6); A[6]=csub(c2,jc6);
  A[1]=cadd(c1,w5);  A[5]=csub(c1,w5);
  A[3]=cadd(c3,w7);  A[7]=csub(c3,w7);
}

__device__ __forceinline__ int slotN(int n){
  return 73*(n >> 6) + (n & 63);
}

// ---------------- kernel 0: transpose cw [E][F][H][2] -> cwT [E][pair][F][4] ----------------
__global__ __launch_bounds__(128) void cwt_kernel(
    const float* __restrict__ cw, float* __restrict__ cwT)
{
  int e = blockIdx.x, fg = blockIdx.y, pr = threadIdx.x;
  const float4* src = (const float4*)cw;
  float4* dst = (float4*)cwT;
  int nf = (fg == 15) ? 17 : 16;
  int f0 = fg * 16;
  for (int i = 0; i < nf; ++i){
    int f = f0 + i;
    dst[(e*128 + pr)*257 + f] = src[(e*257 + f)*128 + pr];
  }
}

// ------------- kernel 1: gate = softmax(mean-pool MLP) / 512, single HBM pass -------------
__global__ __launch_bounds__(256) void gate_kernel(
    const float* __restrict__ x, const float* __restrict__ mlp_w,
    const float* __restrict__ mlp_b, float* __restrict__ gate)
{
  __shared__ float tile[32][257];
  __shared__ float red[32];
  __shared__ int icnt[4];
  int b = blockIdx.x, t = threadIdx.x;
  const float* xb = x + (size_t)b * 131072;

  float colsum = 0.f;
  int cnt = 0;
  for (int ch = 0; ch < 16; ++ch){
    #pragma unroll
    for (int sr = 0; sr < 32; ++sr){
      float v = xb[(ch*32 + sr)*256 + t];
      colsum += v;
      tile[sr][t] = v;
    }
    __syncthreads();
    {
      int row = t >> 3, base = (t & 7) * 32;
      float rs = 0.f;
      #pragma unroll
      for (int j = 0; j < 32; ++j) rs += tile[row][base + j];
      rs += __shfl_xor(rs, 1);
      rs += __shfl_xor(rs, 2);
      rs += __shfl_xor(rs, 4);
      if ((t & 7) == 0) cnt += (rs != 0.f) ? 1 : 0;
    }
    __syncthreads();
  }

  for (int m=1;m<64;m<<=1) cnt += __shfl_xor(cnt, m);
  int wv = t >> 6, ln = t & 63;
  if (ln == 0) icnt[wv] = cnt;
  __syncthreads();
  float valid = (float)(icnt[0]+icnt[1]+icnt[2]+icnt[3]);
  float gi = colsum * (50.0f / ((valid + 1e-4f) * 512.0f));

  float pl[8];
  const float4* w4 = (const float4*)(mlp_w + (size_t)t*8);
  float4 wa = w4[0], wb = w4[1];
  pl[0]=gi*wa.x; pl[1]=gi*wa.y; pl[2]=gi*wa.z; pl[3]=gi*wa.w;
  pl[4]=gi*wb.x; pl[5]=gi*wb.y; pl[6]=gi*wb.z; pl[7]=gi*wb.w;
  #pragma unroll
  for (int e=0;e<8;++e){
    float v = pl[e];
    for (int m=1;m<64;m<<=1) v += __shfl_xor(v, m);
    pl[e] = v;
  }
  if (ln == 0){
    #pragma unroll
    for (int e=0;e<8;++e) red[wv*8+e] = pl[e];
  }
  __syncthreads();
  if (t < 8){
    float lg = red[0*8+t]+red[1*8+t]+red[2*8+t]+red[3*8+t] + mlp_b[t];
    float mx = lg;
    for (int m=1;m<8;m<<=1) mx = fmaxf(mx, __shfl_xor(mx, m, 8));
    float ex = expf(lg - mx);
    float sm = ex;
    for (int m=1;m<8;m<<=1) sm += __shfl_xor(sm, m, 8);
    gate[b*8 + t] = ex / sm * kInv512;
  }
}

// ------- kernel 2 (primary): r6 FFT structure + WAVE-PRIVATE phase C via cwT -------
// Phases B->C->D are one barrier-free wave-private region (wave p owns pair p's
// buffer throughout; CDNA LDS is in-order per wave). cwT's F-fast layout makes
// the per-lane f-indexed filter loads 1KB-contiguous per instruction.
// Only 2 barriers: after cooperative load A, before cooperative store E.
// Plain __launch_bounds__(512): forcing min-waves spilled in r3/r4, and VGPR
// growth killed occupancy in r8 (canaries: WRITE_SIZE == 131072 KB, VGPR <= ~76).
__global__ __launch_bounds__(512) void fft_kernel3(
    const float* __restrict__ x, const float* __restrict__ cwT,
    const float* __restrict__ gate, float* __restrict__ out)
{
  __shared__ float2 zz[8][584];   // 37.4 KB
  int t = threadIdx.x;
  int hg = blockIdx.x, b = blockIdx.y;
  int h_base = hg * 16;
  const float* xb = x + (size_t)b * 131072;
  float* ob = out + (size_t)b * 131072;

  int p = t >> 6, l = t & 63;
  float2* zp = zz[p];
  int k1r = l >> 3, d3 = l & 7;

  // forward twiddles (inverse = conj, applied inline)
  cpx tw1[7], tw2[7];
  {
    float th1 = -6.28318530717958647692f * (1.0f/512.0f) * (float)l;
    cpx w1; __sincosf(th1, &w1.y, &w1.x);
    tw1[0] = w1;
    #pragma unroll
    for (int k=1;k<7;++k) tw1[k] = cmul(tw1[k-1], w1);
    float th2 = -6.28318530717958647692f * (1.0f/64.0f) * (float)d3;
    cpx w2; __sincosf(th2, &w2.y, &w2.x);
    tw2[0] = w2;
    #pragma unroll
    for (int k=1;k<7;++k) tw2[k] = cmul(tw2[k-1], w2);
  }

  float g[8];
  #pragma unroll
  for (int e=0;e<8;++e) g[e] = gate[b*8 + e];

  // phase A: cooperative float2 coalesced load (8 lanes x 8B = 64B chunks)
  #pragma unroll
  for (int it=0; it<8; ++it){
    float2 v = *(const float2*)(xb + (it*64 + (t>>3))*256 + h_base + 2*(t & 7));
    zz[t & 7][73*it + (t >> 3)] = v;
  }
  __syncthreads();

  // ---- phase B: forward FFT (wave-private, no barriers) ----
  {
    cpx a[8];
    #pragma unroll
    for (int j=0;j<8;++j){ float2 v = zp[73*j + l]; a[j] = {v.x, v.y}; }
    dft8<-1>(a);
    #pragma unroll
    for (int k=1;k<8;++k) a[k] = cmul(a[k], tw1[k-1]);
    #pragma unroll
    for (int k1=0;k1<8;++k1) zp[73*k1 + l] = make_float2(a[k1].x, a[k1].y);
    #pragma unroll
    for (int aa=0;aa<8;++aa){ float2 v = zp[73*k1r + 8*aa + d3]; a[aa] = {v.x, v.y}; }
    dft8<-1>(a);
    #pragma unroll
    for (int c=1;c<8;++c) a[c] = cmul(a[c], tw2[c-1]);
    #pragma unroll
    for (int c=0;c<8;++c) zp[73*k1r + 8*c + d3] = make_float2(a[c].x, a[c].y);
    #pragma unroll
    for (int b8=0;b8<8;++b8){ float2 v = zp[73*k1r + 8*d3 + b8]; a[b8] = {v.x, v.y}; }
    dft8<-1>(a);
    int klow = k1r + 8*d3;
    #pragma unroll
    for (int d=0;d<8;++d) zp[73*d + klow] = make_float2(a[d].x, a[d].y);
  }

  // ---- phase C: wave-private Hermitian unpack + (1+w)/512 filter + repack ----
  // lane l handles f = 64*it + l; cwT loads are 64 consecutive float4 / instr.
  {
    int pg = hg*8 + p;
    const float4* cT = (const float4*)cwT;
    #pragma unroll
    for (int it=0; it<4; ++it){
      int f = it*64 + l;                    // 0..255
      float2 Zf = zp[73*it + l];            // slotN(f)
      int m = (512 - f) & 511;
      int sm = slotN(m);
      float2 Zm = zp[sm];
      float X0x = 0.5f*(Zf.x + Zm.x), X0y = 0.5f*(Zf.y - Zm.y);
      float X1x = 0.5f*(Zf.y + Zm.y), X1y = 0.5f*(Zm.x - Zf.x);
      float w0x = kInv512, w0y = 0.f, w1x = kInv512, w1y = 0.f;
      #pragma unroll
      for (int e=0;e<8;++e){
        float4 cv = cT[(e*128 + pg)*257 + f];
        w0x += g[e]*cv.x; w0y += g[e]*cv.y;
        w1x += g[e]*cv.z; w1y += g[e]*cv.w;
      }
      float Y0x = X0x*w0x - X0y*w0y, Y0y = X0x*w0y + X0y*w0x;
      float Y1x = X1x*w1x - X1y*w1y, Y1y = X1x*w1y + X1y*w1x;
      if (f == 0){ Y0y = 0.f; Y1y = 0.f; }  // numpy irfft ignores imag of DC bin
      zp[73*it + l] = make_float2(Y0x - Y1y, Y0y + Y1x);
      zp[sm]        = make_float2(Y0x + Y1y, Y1x - Y0y);
    }
    if (l == 0){  // Nyquist bin f=256: imag of products discarded
      float2 Zf = zp[292];                  // slotN(256)
      float w0x = kInv512, w1x = kInv512;
      #pragma unroll
      for (int e=0;e<8;++e){
        float4 cv = cT[(e*128 + pg)*257 + 256];
        w0x += g[e]*cv.x; w1x += g[e]*cv.z;
      }
      zp[292] = make_float2(Zf.x*w0x, Zf.y*w1x);
    }
  }

  // ---- phase D: inverse FFT (wave-private, conj twiddles) ----
  {
    cpx a[8];
    #pragma unroll
    for (int j=0;j<8;++j){ float2 v = zp[73*j + l]; a[j] = {v.x, v.y}; }
    dft8<1>(a);
    #pragma unroll
    for (int k=1;k<8;++k){ cpx w = tw1[k-1]; a[k] = cpx{ a[k].x*w.x + a[k].y*w.y, a[k].y*w.x - a[k].x*w.y }; }
    #pragma unroll
    for (int k1=0;k1<8;++k1) zp[73*k1 + l] = make_float2(a[k1].x, a[k1].y);
    #pragma unroll
    for (int aa=0;aa<8;++aa){ float2 v = zp[73*k1r + 8*aa + d3]; a[aa] = {v.x, v.y}; }
    dft8<1>(a);
    #pragma unroll
    for (int c=1;c<8;++c){ cpx w = tw2[c-1]; a[c] = cpx{ a[c].x*w.x + a[c].y*w.y, a[c].y*w.x - a[c].x*w.y }; }
    #pragma unroll
    for (int c=0;c<8;++c) zp[73*k1r + 8*c + d3] = make_float2(a[c].x, a[c].y);
    #pragma unroll
    for (int b8=0;b8<8;++b8){ float2 v = zp[73*k1r + 8*d3 + b8]; a[b8] = {v.x, v.y}; }
    dft8<1>(a);
    int klow = k1r + 8*d3;
    #pragma unroll
    for (int d=0;d<8;++d) zp[73*d + klow] = make_float2(a[d].x, a[d].y);
  }
  __syncthreads();

  // phase E: cooperative float2 coalesced writeout
  #pragma unroll
  for (int it=0; it<8; ++it){
    float2 v = zz[t & 7][73*it + (t >> 3)];
    *(float2*)(ob + (it*64 + (t>>3))*256 + h_base + 2*(t & 7)) = v;
  }
}

// ------- kernel 2 (fallback, r6-proven): used when ws_size can't hold cwT -------
__global__ __launch_bounds__(512) void fft_kernel_fb(
    const float* __restrict__ x, const float* __restrict__ cw,
    const float* __restrict__ gate, float* __restrict__ out)
{
  __shared__ float2 zz[8][584];
  int t = threadIdx.x;
  int hg = blockIdx.x, b = blockIdx.y;
  int h_base = hg * 16;
  const float* xb = x + (size_t)b * 131072;
  float* ob = out + (size_t)b * 131072;

  int p = t >> 6, l = t & 63;
  float2* zp = zz[p];
  int k1r = l >> 3, d3 = l & 7;

  cpx tw1[7], tw2[7];
  {
    float th1 = -6.28318530717958647692f * (1.0f/512.0f) * (float)l;
    cpx w1; __sincosf(th1, &w1.y, &w1.x);
    tw1[0] = w1;
    #pragma unroll
    for (int k=1;k<7;++k) tw1[k] = cmul(tw1[k-1], w1);
    float th2 = -6.28318530717958647692f * (1.0f/64.0f) * (float)d3;
    cpx w2; __sincosf(th2, &w2.y, &w2.x);
    tw2[0] = w2;
    #pragma unroll
    for (int k=1;k<7;++k) tw2[k] = cmul(tw2[k-1], w2);
  }

  float g[8];
  #pragma unroll
  for (int e=0;e<8;++e) g[e] = gate[b*8 + e];

  #pragma unroll
  for (int it=0; it<8; ++it){
    int s = it*64 + (t >> 3);
    float2 v = *(const float2*)(xb + s*256 + h_base + 2*(t & 7));
    zz[t & 7][73*it + (t >> 3)] = v;
  }
  __syncthreads();

  {
    cpx a[8];
    #pragma unroll
    for (int j=0;j<8;++j){ float2 v = zp[73*j + l]; a[j] = {v.x, v.y}; }
    dft8<-1>(a);
    #pragma unroll
    for (int k=1;k<8;++k) a[k] = cmul(a[k], tw1[k-1]);
    #pragma unroll
    for (int k1=0;k1<8;++k1) zp[73*k1 + l] = make_float2(a[k1].x, a[k1].y);
    #pragma unroll
    for (int aa=0;aa<8;++aa){ float2 v = zp[73*k1r + 8*aa + d3]; a[aa] = {v.x, v.y}; }
    dft8<-1>(a);
    #pragma unroll
    for (int c=1;c<8;++c) a[c] = cmul(a[c], tw2[c-1]);
    #pragma unroll
    for (int c=0;c<8;++c) zp[73*k1r + 8*c + d3] = make_float2(a[c].x, a[c].y);
    #pragma unroll
    for (int b8=0;b8<8;++b8){ float2 v = zp[73*k1r + 8*d3 + b8]; a[b8] = {v.x, v.y}; }
    dft8<-1>(a);
    int klow = k1r + 8*d3;
    #pragma unroll
    for (int d=0;d<8;++d) zp[73*d + klow] = make_float2(a[d].x, a[d].y);
  }
  __syncthreads();

  {
    int pc = t & 7, fq = t >> 3;
    float2* zq = zz[pc];
    int hc = h_base + 2*pc;
    #pragma unroll
    for (int it=0; it<4; ++it){
      int f = it*64 + fq;
      float2 Zf = zq[73*it + fq];
      int m = (512 - f) & 511;
      float2 Zm = zq[slotN(m)];
      float X0x = 0.5f*(Zf.x + Zm.x), X0y = 0.5f*(Zf.y - Zm.y);
      float X1x = 0.5f*(Zf.y + Zm.y), X1y = 0.5f*(Zm.x - Zf.x);
      float w0x = kInv512, w0y = 0.f, w1x = kInv512, w1y = 0.f;
      const float* cwf = cw + ((size_t)f*256 + hc)*2;
      #pragma unroll
      for (int e=0;e<8;++e){
        float4 cv = *(const float4*)(cwf + (size_t)e*131584);
        w0x += g[e]*cv.x; w0y += g[e]*cv.y;
        w1x += g[e]*cv.z; w1y += g[e]*cv.w;
      }
      float Y0x = X0x*w0x - X0y*w0y, Y0y = X0x*w0y + X0y*w0x;
      float Y1x = X1x*w1x - X1y*w1y, Y1y = X1x*w1y + X1y*w1x;
      if (f == 0){ Y0y = 0.f; Y1y = 0.f; }
      zq[73*it + fq] = make_float2(Y0x - Y1y, Y0y + Y1x);
      zq[slotN(m)]   = make_float2(Y0x + Y1y, Y1x - Y0y);
    }
    if (t < 8){
      float2* zn = zz[t];
      int hn = h_base + 2*t;
      float2 Zf = zn[292];
      float w0x = kInv512, w1x = kInv512;
      const float* cwf = cw + ((size_t)256*256 + hn)*2;
      #pragma unroll
      for (int e=0;e<8;++e){
        float4 cv = *(const float4*)(cwf + (size_t)e*131584);
        w0x += g[e]*cv.x; w1x += g[e]*cv.z;
      }
      zn[292] = make_float2(Zf.x*w0x, Zf.y*w1x);
    }
  }
  __syncthreads();

  {
    cpx a[8];
    #pragma unroll
    for (int j=0;j<8;++j){ float2 v = zp[73*j + l]; a[j] = {v.x, v.y}; }
    dft8<1>(a);
    #pragma unroll
    for (int k=1;k<8;++k){ cpx w = tw1[k-1]; a[k] = cpx{ a[k].x*w.x + a[k].y*w.y, a[k].y*w.x - a[k].x*w.y }; }
    #pragma unroll
    for (int k1=0;k1<8;++k1) zp[73*k1 + l] = make_float2(a[k1].x, a[k1].y);
    #pragma unroll
    for (int aa=0;aa<8;++aa){ float2 v = zp[73*k1r + 8*aa + d3]; a[aa] = {v.x, v.y}; }
    dft8<1>(a);
    #pragma unroll
    for (int c=1;c<8;++c){ cpx w = tw2[c-1]; a[c] = cpx{ a[c].x*w.x + a[c].y*w.y, a[c].y*w.x - a[c].x*w.y }; }
    #pragma unroll
    for (int c=0;c<8;++c) zp[73*k1r + 8*c + d3] = make_float2(a[c].x, a[c].y);
    #pragma unroll
    for (int b8=0;b8<8;++b8){ float2 v = zp[73*k1r + 8*d3 + b8]; a[b8] = {v.x, v.y}; }
    dft8<1>(a);
    int klow = k1r + 8*d3;
    #pragma unroll
    for (int d=0;d<8;++d) zp[73*d + klow] = make_float2(a[d].x, a[d].y);
  }
  __syncthreads();

  #pragma unroll
  for (int it=0; it<8; ++it){
    int s = it*64 + (t >> 3);
    float2 v = zz[t & 7][73*it + (t >> 3)];
    *(float2*)(ob + s*256 + h_base + 2*(t & 7)) = v;
  }
}

// ---------------- kernel 3: in-place LayerNorm over H=256 ----------------
__global__ __launch_bounds__(256) void ln_kernel(
    float* __restrict__ io, const float* __restrict__ gamma,
    const float* __restrict__ beta)
{
  int t = threadIdx.x;
  int row = blockIdx.x*4 + (t >> 6);
  int ln = t & 63;
  float4* pr = (float4*)(io + (size_t)row * 256);
  float4 v = pr[ln];
  float s = (v.x+v.y)+(v.z+v.w);
  float q = (v.x*v.x + v.y*v.y) + (v.z*v.z + v.w*v.w);
  for (int m=1;m<64;m<<=1){ s += __shfl_xor(s, m); q += __shfl_xor(q, m); }
  float mean = s * (1.0f/256.0f);
  float var  = q * (1.0f/256.0f) - mean*mean;
  float rstd = rsqrtf(var + 1e-12f);
  const float4 gm = ((const float4*)gamma)[ln];
  const float4 bt = ((const float4*)beta)[ln];
  float4 o;
  o.x = (v.x - mean)*rstd*gm.x + bt.x;
  o.y = (v.y - mean)*rstd*gm.y + bt.y;
  o.z = (v.z - mean)*rstd*gm.z + bt.z;
  o.w = (v.w - mean)*rstd*gm.w + bt.w;
  pr[ln] = o;
}

} // anonymous namespace

extern "C" void kernel_launch(void* const* d_in, const int* in_sizes, int n_in,
                              void* d_out, int out_size, void* d_ws, size_t ws_size,
                              hipStream_t stream) {
  const float* x     = (const float*)d_in[0];
  const float* cw    = (const float*)d_in[1];
  const float* mlp_w = (const float*)d_in[2];
  const float* mlp_b = (const float*)d_in[3];
  const float* gamma = (const float*)d_in[4];
  const float* beta  = (const float*)d_in[5];
  float* out  = (float*)d_out;          // h-scratch, then LN'd in place
  float* gate = (float*)d_ws;           // 2048 floats (8 KB)

  hipLaunchKernelGGL(gate_kernel, dim3(256), dim3(256), 0, stream,
                     x, mlp_w, mlp_b, gate);

  const size_t cwT_bytes = (size_t)8*128*257*4*sizeof(float); // 4.21 MB
  if (ws_size >= 8192 + cwT_bytes){
    float* cwT = (float*)((char*)d_ws + 8192);
    hipLaunchKernelGGL(cwt_kernel, dim3(8,16), dim3(128), 0, stream, cw, cwT);
    hipLaunchKernelGGL(fft_kernel3, dim3(16, 256), dim3(512), 0, stream,
                       x, cwT, gate, out);
  } else {
    hipLaunchKernelGGL(fft_kernel_fb, dim3(16, 256), dim3(512), 0, stream,
                       x, cw, gate, out);
  }

  hipLaunchKernelGGL(ln_kernel, dim3(32768), dim3(256), 0, stream,
                     out, gamma, beta);
}

// Round 10
// 186.139 us; speedup vs baseline: 1.6879x; 1.2948x over previous
//
#include <hip/hip_runtime.h>
#include <math.h>

namespace {

constexpr float kInv512 = 1.0f / 512.0f;

struct cpx { float x, y; };
__device__ __forceinline__ cpx cadd(cpx a, cpx b){ return {a.x+b.x, a.y+b.y}; }
__device__ __forceinline__ cpx csub(cpx a, cpx b){ return {a.x-b.x, a.y-b.y}; }
__device__ __forceinline__ cpx cmul(cpx a, cpx b){ return {a.x*b.x - a.y*b.y, a.x*b.y + a.y*b.x}; }

// multiply by (S<0 ? -i : +i)
template<int S>
__device__ __forceinline__ cpx Jrot(cpx z){
  return (S < 0) ? cpx{ z.y, -z.x } : cpx{ -z.y, z.x };
}

// natural-order 8-point DFT, A[k] = sum_n A[n] * exp(S*2*pi*i*n*k/8)
template<int S>
__device__ __forceinline__ void dft8(cpx* A){
  const float s2 = 0.70710678118654752440f;
  cpx t0=A[0], t1=A[4], t2=A[2], t3=A[6], t4=A[1], t5=A[5], t6=A[3], t7=A[7];
  cpx b0=cadd(t0,t1), b1=csub(t0,t1), b2=cadd(t2,t3), b3=csub(t2,t3);
  cpx b4=cadd(t4,t5), b5=csub(t4,t5), b6=cadd(t6,t7), b7=csub(t6,t7);
  cpx jb3=Jrot<S>(b3), jb7=Jrot<S>(b7);
  cpx c0=cadd(b0,b2), c2=csub(b0,b2), c1=cadd(b1,jb3), c3=csub(b1,jb3);
  cpx c4=cadd(b4,b6), c6=csub(b4,b6), c5=cadd(b5,jb7), c7=csub(b5,jb7);
  cpx jc6=Jrot<S>(c6);
  cpx w5, w7;
  if (S < 0) {
    w5 = cpx{ s2*(c5.x + c5.y), s2*(c5.y - c5.x) };   // w8^1 * c5
    w7 = cpx{ s2*(c7.y - c7.x), -s2*(c7.x + c7.y) };  // w8^3 * c7
  } else {
    w5 = cpx{ s2*(c5.x - c5.y), s2*(c5.x + c5.y) };
    w7 = cpx{ -s2*(c7.x + c7.y), s2*(c7.x - c7.y) };
  }
  A[0]=cadd(c0,c4); A[4]=csub(c0,c4);
  A[2]=cadd(c2,jc6); A[6]=csub(c2,jc6);
  A[1]=cadd(c1,w5);  A[5]=csub(c1,w5);
  A[3]=cadd(c3,w7);  A[7]=csub(c3,w7);
}

// Layout: slot(n) = 73*(n>>6) + (n&63); pair stride 584 float2.
__device__ __forceinline__ int slotN(int n){
  return 73*(n >> 6) + (n & 63);
}

// ------------- kernel 1a: partial raw logits + valid count per (b, s-quarter) -------------
// logit[e] = scale(valid) * sum_h colsum[h]*W[h][e] is LINEAR in x -> partial-
// sum decomposable over s-ranges. 1024 blocks => 4 blocks/CU (vs 1 before).
// ws layout: ws[blk*12 + e] = partial raw logit e, ws[blk*12 + 8] = partial count.
__global__ __launch_bounds__(256) void gate1_kernel(
    const float* __restrict__ x, const float* __restrict__ mlp_w,
    float* __restrict__ ws)
{
  __shared__ float tile[32][257];   // padded -> conflict-free
  __shared__ float red[32];
  __shared__ int icnt[4];
  int blk = blockIdx.x, t = threadIdx.x;
  int b = blk >> 2, q = blk & 3;
  const float* xb = x + (size_t)b * 131072 + (size_t)q * 32768;  // 128 rows

  float colsum = 0.f;
  int cnt = 0;
  for (int ch = 0; ch < 4; ++ch){
    #pragma unroll
    for (int sr = 0; sr < 32; ++sr){
      float v = xb[(ch*32 + sr)*256 + t];
      colsum += v;
      tile[sr][t] = v;
    }
    __syncthreads();
    {
      int row = t >> 3, base = (t & 7) * 32;
      float rs = 0.f;
      #pragma unroll
      for (int j = 0; j < 32; ++j) rs += tile[row][base + j];
      rs += __shfl_xor(rs, 1);
      rs += __shfl_xor(rs, 2);
      rs += __shfl_xor(rs, 4);
      if ((t & 7) == 0) cnt += (rs != 0.f) ? 1 : 0;
    }
    __syncthreads();
  }

  // block-reduce valid-row count
  for (int m=1;m<64;m<<=1) cnt += __shfl_xor(cnt, m);
  int wv = t >> 6, ln = t & 63;
  if (ln == 0) icnt[wv] = cnt;

  // partial raw logits: colsum[h=t] dot mlp_w[t][e]
  float pl[8];
  const float4* w4 = (const float4*)(mlp_w + (size_t)t*8);
  float4 wa = w4[0], wb = w4[1];
  pl[0]=colsum*wa.x; pl[1]=colsum*wa.y; pl[2]=colsum*wa.z; pl[3]=colsum*wa.w;
  pl[4]=colsum*wb.x; pl[5]=colsum*wb.y; pl[6]=colsum*wb.z; pl[7]=colsum*wb.w;
  #pragma unroll
  for (int e=0;e<8;++e){
    float v = pl[e];
    for (int m=1;m<64;m<<=1) v += __shfl_xor(v, m);
    pl[e] = v;
  }
  if (ln == 0){
    #pragma unroll
    for (int e=0;e<8;++e) red[wv*8+e] = pl[e];
  }
  __syncthreads();
  if (t < 8){
    ws[blk*12 + t] = red[0*8+t]+red[1*8+t]+red[2*8+t]+red[3*8+t];
  }
  if (t == 8){
    ws[blk*12 + 8] = (float)(icnt[0]+icnt[1]+icnt[2]+icnt[3]);
  }
}

// ------------- kernel 1b: combine partials -> gate = softmax(...)/512 -------------
// One 256-thread block; thread t = batch b.
__global__ __launch_bounds__(256) void gate2_kernel(
    const float* __restrict__ ws, const float* __restrict__ mlp_b,
    float* __restrict__ gate)
{
  int b = threadIdx.x;
  float raw[8] = {0,0,0,0,0,0,0,0};
  float valid = 0.f;
  #pragma unroll
  for (int q=0;q<4;++q){
    int base = (b*4 + q)*12;
    #pragma unroll
    for (int e=0;e<8;++e) raw[e] += ws[base + e];
    valid += ws[base + 8];
  }
  float scale = 50.0f / ((valid + 1e-4f) * 512.0f);
  float lg[8], mx = -1e30f;
  #pragma unroll
  for (int e=0;e<8;++e){ lg[e] = raw[e]*scale + mlp_b[e]; mx = fmaxf(mx, lg[e]); }
  float sm = 0.f;
  #pragma unroll
  for (int e=0;e<8;++e){ lg[e] = expf(lg[e] - mx); sm += lg[e]; }
  float inv = kInv512 / sm;   // fold ortho^2 = 1/512
  #pragma unroll
  for (int e=0;e<8;++e) gate[b*8 + e] = lg[e] * inv;
}

// ------------- kernel 2: per (b, 16-channel group): FFT * (1+w) -> h -----------
// r6-proven config: stride-73 LDS, hoisted twiddles, 4 barriers, block-
// cooperative phase C on cw directly. Plain __launch_bounds__(512): forcing
// min-waves spilled in r3/r4; VGPR growth killed occupancy in r8
// (canaries: WRITE_SIZE == 131072 KB, VGPR <= ~76).
__global__ __launch_bounds__(512) void fft_kernel(
    const float* __restrict__ x, const float* __restrict__ cw,
    const float* __restrict__ gate, float* __restrict__ out)
{
  __shared__ float2 zz[8][584];   // 8 pairs, stride 584 float2 (37.4 KB)
  int t = threadIdx.x;
  int hg = blockIdx.x, b = blockIdx.y;
  int h_base = hg * 16;
  const float* xb = x + (size_t)b * 131072;
  float* ob = out + (size_t)b * 131072;

  int p = t >> 6, l = t & 63;     // wave p handles pair p -> channels h0, h0+1
  float2* zp = zz[p];
  int k1r = l >> 3, d3 = l & 7;

  // hoisted twiddles (forward values; inverse = conj applied inline)
  cpx tw1[7], tw2[7];
  {
    float th1 = -6.28318530717958647692f * (1.0f/512.0f) * (float)l;
    cpx w1; __sincosf(th1, &w1.y, &w1.x);
    tw1[0] = w1;
    #pragma unroll
    for (int k=1;k<7;++k) tw1[k] = cmul(tw1[k-1], w1);
    float th2 = -6.28318530717958647692f * (1.0f/64.0f) * (float)d3;
    cpx w2; __sincosf(th2, &w2.y, &w2.x);
    tw2[0] = w2;
    #pragma unroll
    for (int k=1;k<7;++k) tw2[k] = cmul(tw2[k-1], w2);
  }

  // gate values (uniform per block)
  float g[8];
  #pragma unroll
  for (int e=0;e<8;++e) g[e] = gate[b*8 + e];

  // phase A: float2 coalesced load (8 lanes x 8B = 64B contiguous chunks)
  #pragma unroll
  for (int it=0; it<8; ++it){
    int s = it*64 + (t >> 3);
    float2 v = *(const float2*)(xb + s*256 + h_base + 2*(t & 7));
    zz[t & 7][73*it + (t >> 3)] = v;    // slotN(s), row = it
  }
  __syncthreads();

  // phase B: forward FFT of packed z = x[:,h0] + i*x[:,h1]
  {
    cpx a[8];
    #pragma unroll
    for (int j=0;j<8;++j){ float2 v = zp[73*j + l]; a[j] = {v.x, v.y}; }
    dft8<-1>(a);
    #pragma unroll
    for (int k=1;k<8;++k) a[k] = cmul(a[k], tw1[k-1]);
    #pragma unroll
    for (int k1=0;k1<8;++k1) zp[73*k1 + l] = make_float2(a[k1].x, a[k1].y);
    #pragma unroll
    for (int aa=0;aa<8;++aa){ float2 v = zp[73*k1r + 8*aa + d3]; a[aa] = {v.x, v.y}; }
    dft8<-1>(a);
    #pragma unroll
    for (int c=1;c<8;++c) a[c] = cmul(a[c], tw2[c-1]);
    #pragma unroll
    for (int c=0;c<8;++c) zp[73*k1r + 8*c + d3] = make_float2(a[c].x, a[c].y);
    #pragma unroll
    for (int b8=0;b8<8;++b8){ float2 v = zp[73*k1r + 8*d3 + b8]; a[b8] = {v.x, v.y}; }
    dft8<-1>(a);
    int klow = k1r + 8*d3;
    #pragma unroll
    for (int d=0;d<8;++d) zp[73*d + klow] = make_float2(a[d].x, a[d].y);
  }
  __syncthreads();

  // phase C (block-cooperative): unpack rfft's, apply (1 + w)/512, repack.
  // item (f, pair): pair = t&7, f = it*64 + (t>>3)  ->  8 consecutive lanes
  // read 8 consecutive float4s of cw = 128B contiguous, fully-used lines.
  {
    int pc = t & 7, fq = t >> 3;
    float2* zq = zz[pc];
    int hc = h_base + 2*pc;
    #pragma unroll
    for (int it=0; it<4; ++it){
      int f = it*64 + fq;                   // 0..255
      float2 Zf = zq[73*it + fq];           // slotN(f)
      int m = (512 - f) & 511;
      float2 Zm = zq[slotN(m)];
      float X0x = 0.5f*(Zf.x + Zm.x), X0y = 0.5f*(Zf.y - Zm.y);
      float X1x = 0.5f*(Zf.y + Zm.y), X1y = 0.5f*(Zm.x - Zf.x);
      float w0x = kInv512, w0y = 0.f, w1x = kInv512, w1y = 0.f;
      const float* cwf = cw + ((size_t)f*256 + hc)*2;
      #pragma unroll
      for (int e=0;e<8;++e){
        float4 cv = *(const float4*)(cwf + (size_t)e*131584);  // 257*512
        w0x += g[e]*cv.x; w0y += g[e]*cv.y;
        w1x += g[e]*cv.z; w1y += g[e]*cv.w;
      }
      float Y0x = X0x*w0x - X0y*w0y, Y0y = X0x*w0y + X0y*w0x;
      float Y1x = X1x*w1x - X1y*w1y, Y1y = X1x*w1y + X1y*w1x;
      if (f == 0){ Y0y = 0.f; Y1y = 0.f; }  // numpy irfft ignores imag of DC bin
      zq[73*it + fq] = make_float2(Y0x - Y1y, Y0y + Y1x);
      zq[slotN(m)]   = make_float2(Y0x + Y1y, Y1x - Y0y);
    }
    if (t < 8){  // Nyquist bin f=256 for pair p=t: imag of products discarded
      float2* zn = zz[t];
      int hn = h_base + 2*t;
      float2 Zf = zn[292];                  // slotN(256) = 73*4
      float w0x = kInv512, w1x = kInv512;
      const float* cwf = cw + ((size_t)256*256 + hn)*2;
      #pragma unroll
      for (int e=0;e<8;++e){
        float4 cv = *(const float4*)(cwf + (size_t)e*131584);
        w0x += g[e]*cv.x; w1x += g[e]*cv.z;
      }
      zn[292] = make_float2(Zf.x*w0x, Zf.y*w1x);
    }
  }
  __syncthreads();

  // phase D: inverse FFT (conj twiddles) -> h = y + x (folded via 1+w)
  {
    cpx a[8];
    #pragma unroll
    for (int j=0;j<8;++j){ float2 v = zp[73*j + l]; a[j] = {v.x, v.y}; }
    dft8<1>(a);
    #pragma unroll
    for (int k=1;k<8;++k){ cpx w = tw1[k-1]; a[k] = cpx{ a[k].x*w.x + a[k].y*w.y, a[k].y*w.x - a[k].x*w.y }; }
    #pragma unroll
    for (int k1=0;k1<8;++k1) zp[73*k1 + l] = make_float2(a[k1].x, a[k1].y);
    #pragma unroll
    for (int aa=0;aa<8;++aa){ float2 v = zp[73*k1r + 8*aa + d3]; a[aa] = {v.x, v.y}; }
    dft8<1>(a);
    #pragma unroll
    for (int c=1;c<8;++c){ cpx w = tw2[c-1]; a[c] = cpx{ a[c].x*w.x + a[c].y*w.y, a[c].y*w.x - a[c].x*w.y }; }
    #pragma unroll
    for (int c=0;c<8;++c) zp[73*k1r + 8*c + d3] = make_float2(a[c].x, a[c].y);
    #pragma unroll
    for (int b8=0;b8<8;++b8){ float2 v = zp[73*k1r + 8*d3 + b8]; a[b8] = {v.x, v.y}; }
    dft8<1>(a);
    int klow = k1r + 8*d3;
    #pragma unroll
    for (int d=0;d<8;++d) zp[73*d + klow] = make_float2(a[d].x, a[d].y);
  }
  __syncthreads();

  // phase E: float2 coalesced writeout (same 64B-chunk pattern as phase A)
  #pragma unroll
  for (int it=0; it<8; ++it){
    int s = it*64 + (t >> 3);
    float2 v = zz[t & 7][73*it + (t >> 3)];
    *(float2*)(ob + s*256 + h_base + 2*(t & 7)) = v;
  }
}

// ---------------- kernel 3: in-place LayerNorm over H=256 ----------------
__global__ __launch_bounds__(256) void ln_kernel(
    float* __restrict__ io, const float* __restrict__ gamma,
    const float* __restrict__ beta)
{
  int t = threadIdx.x;
  int row = blockIdx.x*4 + (t >> 6);
  int ln = t & 63;
  float4* pr = (float4*)(io + (size_t)row * 256);
  float4 v = pr[ln];
  float s = (v.x+v.y)+(v.z+v.w);
  float q = (v.x*v.x + v.y*v.y) + (v.z*v.z + v.w*v.w);
  for (int m=1;m<64;m<<=1){ s += __shfl_xor(s, m); q += __shfl_xor(q, m); }
  float mean = s * (1.0f/256.0f);
  float var  = q * (1.0f/256.0f) - mean*mean;
  float rstd = rsqrtf(var + 1e-12f);
  const float4 gm = ((const float4*)gamma)[ln];
  const float4 bt = ((const float4*)beta)[ln];
  float4 o;
  o.x = (v.x - mean)*rstd*gm.x + bt.x;
  o.y = (v.y - mean)*rstd*gm.y + bt.y;
  o.z = (v.z - mean)*rstd*gm.z + bt.z;
  o.w = (v.w - mean)*rstd*gm.w + bt.w;
  pr[ln] = o;
}

} // anonymous namespace

extern "C" void kernel_launch(void* const* d_in, const int* in_sizes, int n_in,
                              void* d_out, int out_size, void* d_ws, size_t ws_size,
                              hipStream_t stream) {
  const float* x     = (const float*)d_in[0];
  const float* cw    = (const float*)d_in[1];
  const float* mlp_w = (const float*)d_in[2];
  const float* mlp_b = (const float*)d_in[3];
  const float* gamma = (const float*)d_in[4];
  const float* beta  = (const float*)d_in[5];
  float* out  = (float*)d_out;            // h-scratch, then LN'd in place
  float* part = (float*)d_ws;             // 1024*12 floats = 48 KB partials
  float* gate = part + 1024*12;           // 256*8 floats

  hipLaunchKernelGGL(gate1_kernel, dim3(1024), dim3(256), 0, stream,
                     x, mlp_w, part);
  hipLaunchKernelGGL(gate2_kernel, dim3(1), dim3(256), 0, stream,
                     part, mlp_b, gate);
  hipLaunchKernelGGL(fft_kernel, dim3(16, 256), dim3(512), 0, stream,
                     x, cw, gate, out);
  hipLaunchKernelGGL(ln_kernel, dim3(32768), dim3(256), 0, stream,
                     out, gamma, beta);
}